// Round 5
// baseline (99.486 us; speedup 1.0000x reference)
//
#include <hip/hip_runtime.h>
#include <math.h>

#define Bsz 8
#define NP 9
#define OC 8
#define TILE 256          // pixels per block
#define BPB 64            // blocks per batch = 16384 / TILE
#define THREADS 256
#define ACC_PER (OC * NP * 5)   // 360 accumulators
#define NCOPY 16                // accumulator replicas (4 waves x 4 lane-groups)

// Kernel 1, templated atomic flavor:
//   VARIANT 0: plain atomicAdd (round-3/4 baseline, suspected CAS loop)
//   VARIANT 1: __hip_atomic_fetch_add relaxed/workgroup (expected ds_add_f32)
template <int VARIANT>
__global__ __launch_bounds__(THREADS) void cls_vote_partial(
    const float* __restrict__ seg, const float* __restrict__ direct,
    const float* __restrict__ wts, float* __restrict__ partial)
{
    __shared__ float ls_seg[TILE * 9];    //  9216 B (576 float4)
    __shared__ float ls_dir[TILE * 18];   // 18432 B (1152 float4)
    __shared__ float ls_w[TILE * 9];      //  9216 B (576 float4)
    __shared__ float acc[NCOPY][ACC_PER]; // 23040 B   (total 59904 B -> 2 blk/CU)

    const int b = blockIdx.y;
    const int tid = threadIdx.x;
    const int blkpix = blockIdx.x * TILE;
    const long gbase = (long)b * 16384 + blkpix;

    // zero accumulators
    for (int i = tid; i < NCOPY * ACC_PER; i += THREADS) ((float*)acc)[i] = 0.f;

    // coalesced float4 staging
    {
        const float4* gs = (const float4*)(seg + gbase * 9);     // 576 float4
        const float4* gd = (const float4*)(direct + gbase * 18); // 1152 float4
        const float4* gw = (const float4*)(wts + gbase * 9);     // 576 float4
        float4* s4 = (float4*)ls_seg;
        float4* d4 = (float4*)ls_dir;
        float4* w4 = (float4*)ls_w;
#pragma unroll
        for (int k = 0; k < 2; ++k) s4[tid + k * THREADS] = gs[tid + k * THREADS];
        if (tid < 64) s4[tid + 512] = gs[tid + 512];             // 512..575
#pragma unroll
        for (int k = 0; k < 4; ++k) d4[tid + k * THREADS] = gd[tid + k * THREADS];
        if (tid < 128) d4[tid + 1024] = gd[tid + 1024];          // 1024..1151
#pragma unroll
        for (int k = 0; k < 2; ++k) w4[tid + k * THREADS] = gw[tid + k * THREADS];
        if (tid < 64) w4[tid + 512] = gw[tid + 512];             // 512..575
    }
    __syncthreads();

    // compute phase: one pixel per thread
    {
        const int pix = tid;
        const int h = (blkpix + pix) >> 7;
        const int x = (blkpix + pix) & 127;
        const float* s = ls_seg + pix * 9;

        float m = s[0];
        int am = 0;
#pragma unroll
        for (int c = 1; c < 9; ++c) {
            float v = s[c];
            if (v > m) { m = v; am = c; }
        }
        if (am != 0) {
            const int cls = am - 1;
            float* a = acc[((tid >> 6) << 2) | (tid & 3)] + cls * (NP * 5);
            const float ch = (h + 0.5f) * 0.0078125f;
            const float cw = (x + 0.5f) * 0.0078125f;
            const float* dd = ls_dir + pix * 18;
            const float* wv = ls_w + pix * 9;
#pragma unroll
            for (int p = 0; p < NP; ++p) {
                float wx = wv[p];
                float e = __expf(wx);
                float sp = (wx > 15.f) ? wx : __logf(1.f + e);
                float nx = dd[2 * p], ny = dd[2 * p + 1];
                float nn = nx * nx + ny * ny;
                float R00, R01, R11;
                if (nn > 0.f) {
                    float inv = __builtin_amdgcn_rcpf(nn);
                    R00 = sp * (1.f - nx * nx * inv);
                    R01 = -sp * (nx * ny * inv);
                    R11 = sp * (1.f - ny * ny * inv);
                } else {  // divide_no_nan: n == 0 -> R = w * I
                    R00 = sp; R01 = 0.f; R11 = sp;
                }
                float q0 = R00 * ch + R01 * cw;
                float q1 = R01 * ch + R11 * cw;
                float vals[5] = {R00, R01, R11, q0, q1};
#pragma unroll
                for (int f = 0; f < 5; ++f) {
                    if (VARIANT == 0) {
                        atomicAdd(&a[p * 5 + f], vals[f]);
                    } else {
                        __hip_atomic_fetch_add(&a[p * 5 + f], vals[f],
                                               __ATOMIC_RELAXED,
                                               __HIP_MEMORY_SCOPE_WORKGROUP);
                    }
                }
            }
        }
    }
    __syncthreads();

    // reduce 16 copies -> block partial
    float* outp = partial + (long)(b * BPB + blockIdx.x) * ACC_PER;
    for (int i = tid; i < ACC_PER; i += THREADS) {
        float sv = 0.f;
#pragma unroll
        for (int k = 0; k < NCOPY; ++k) sv += acc[k][i];
        outp[i] = sv;
    }
}

// Kernel 2: 4 lanes per (b,cls,p) sum 64 block partials in f64,
// butterfly-reduce, 2x2 solve, scale by HEIGHT=128.
__global__ void cls_vote_solve(const float* __restrict__ partial,
                               float* __restrict__ out)
{
    int t = blockIdx.x * blockDim.x + threadIdx.x;
    if (t >= Bsz * OC * NP * 4) return;
    const int g = t & 3;
    const int id = t >> 2;          // (b, cls*9+p)
    const int b = id / (OC * NP);
    const int r = id % (OC * NP);

    double a = 0, bb = 0, c = 0, q0 = 0, q1 = 0;
    const float* base = partial + (long)b * BPB * ACC_PER + r * 5;
#pragma unroll 4
    for (int blk = g; blk < BPB; blk += 4) {
        const float* pp = base + blk * ACC_PER;
        a  += (double)pp[0];
        bb += (double)pp[1];
        c  += (double)pp[2];
        q0 += (double)pp[3];
        q1 += (double)pp[4];
    }
#pragma unroll
    for (int off = 1; off < 4; off <<= 1) {
        a  += __shfl_xor(a, off, 64);
        bb += __shfl_xor(bb, off, 64);
        c  += __shfl_xor(c, off, 64);
        q0 += __shfl_xor(q0, off, 64);
        q1 += __shfl_xor(q1, off, 64);
    }
    if (g == 0) {
        double det = a * c - bb * bb;
        double p0 = 0.0, p1 = 0.0;
        if (det != 0.0) {
            double ia = c / det, ib = -bb / det, ic = a / det;
            p0 = ia * q0 + ib * q1;
            p1 = ib * q0 + ic * q1;
        }
        out[2 * id + 0] = (float)(p0 * 128.0);
        out[2 * id + 1] = (float)(p1 * 128.0);
    }
}

extern "C" void kernel_launch(void* const* d_in, const int* in_sizes, int n_in,
                              void* d_out, int out_size, void* d_ws, size_t ws_size,
                              hipStream_t stream) {
    const float* seg    = (const float*)d_in[0];
    const float* direct = (const float*)d_in[1];
    const float* wts    = (const float*)d_in[2];
    float* out = (float*)d_out;
    float* partial1 = (float*)d_ws;              // V0 output (feeds kernel 2)
    float* partial2 = (float*)d_ws + 184320;     // V1 probe output (unused)
    float* partial3 = (float*)d_ws + 368640;     // V1 probe output (unused)

    dim3 grid1(BPB, Bsz);
    // Differential probe: dur = V0 + 2*V1 + k2 + overhead.
    // Round-3 anchor (V0 + k2 + ovh) = 39.2us  =>  V1 cost = (dur - 39.2)/2.
    cls_vote_partial<0><<<grid1, THREADS, 0, stream>>>(seg, direct, wts, partial1);
    cls_vote_partial<1><<<grid1, THREADS, 0, stream>>>(seg, direct, wts, partial2);
    cls_vote_partial<1><<<grid1, THREADS, 0, stream>>>(seg, direct, wts, partial3);

    int total = Bsz * OC * NP * 4;  // 2304
    cls_vote_solve<<<(total + 255) / 256, 256, 0, stream>>>(partial1, out);
}

// Round 6
// 21.377 us; speedup vs baseline: 4.6540x; 4.6540x over previous
//
#include <hip/hip_runtime.h>
#include <math.h>

#define Bsz 8
#define NP 9
#define OC 8
#define TILE 256           // pixels per block
#define BPB 64             // blocks per batch
#define THREADS 256
#define ACC_PER (OC * NP * 5)    // 360 per-block partial values
#define VROW 15                  // u32 words per vals row (27 u16 + pad; 15 coprime 32)

__device__ inline unsigned short f2bf(float v) {   // RNE f32 -> bf16 bits
    unsigned u = __float_as_uint(v);
    return (unsigned short)((u + 0x7FFF + ((u >> 16) & 1)) >> 16);
}
__device__ inline float bf2f(unsigned short u) {
    return __uint_as_float((unsigned)u << 16);
}

// Kernel 1: per-block class-gather reduction, zero atomics.
// Phase A (pixel-parallel): argmax class + 27 R-entries -> LDS (plain writes).
// Phase B (bucket-parallel): 216 threads = (8 cls x 9 pts x 3 slices) scan the
// tile, accumulate R sums + coord-weighted q sums in REGISTERS.
__global__ __launch_bounds__(THREADS) void cls_vote_partial(
    const float* __restrict__ seg, const float* __restrict__ direct,
    const float* __restrict__ wts, float* __restrict__ partial)
{
    __shared__ float ls_seg[TILE * 9];          //  9216 B
    __shared__ float ls_dir[TILE * 18];         // 18432 B
    __shared__ float ls_w[TILE * 9];            //  9216 B
    __shared__ unsigned ls_vals[TILE * VROW];   // 15360 B (bf16-packed R rows)
    __shared__ int ls_cls[TILE + 8];            //  1056 B (+pad for scan overrun)
    __shared__ float ls_merge[216][5];          //  4320 B
                                                // total 57600 B -> 2 blocks/CU
    const int b = blockIdx.y;
    const int tid = threadIdx.x;
    const long gbase = (long)b * 16384 + blockIdx.x * TILE;

    // ---- coalesced float4 staging (verified round 3) ----
    {
        const float4* gs = (const float4*)(seg + gbase * 9);     // 576 float4
        const float4* gd = (const float4*)(direct + gbase * 18); // 1152 float4
        const float4* gw = (const float4*)(wts + gbase * 9);     // 576 float4
        float4* s4 = (float4*)ls_seg;
        float4* d4 = (float4*)ls_dir;
        float4* w4 = (float4*)ls_w;
#pragma unroll
        for (int k = 0; k < 2; ++k) s4[tid + k * THREADS] = gs[tid + k * THREADS];
        if (tid < 64) s4[tid + 512] = gs[tid + 512];
#pragma unroll
        for (int k = 0; k < 4; ++k) d4[tid + k * THREADS] = gd[tid + k * THREADS];
        if (tid < 128) d4[tid + 1024] = gd[tid + 1024];
#pragma unroll
        for (int k = 0; k < 2; ++k) w4[tid + k * THREADS] = gw[tid + k * THREADS];
        if (tid < 64) w4[tid + 512] = gw[tid + 512];
    }
    __syncthreads();

    // ---- Phase A: per-pixel class + R entries (plain LDS writes) ----
    {
        const int pix = tid;
        const float* s = ls_seg + pix * 9;
        float m = s[0];
        int am = 0;
#pragma unroll
        for (int c = 1; c < 9; ++c) {
            float v = s[c];
            if (v > m) { m = v; am = c; }
        }
        ls_cls[pix] = am - 1;                 // -1 = background
        if (tid < 8) ls_cls[TILE + tid] = -1; // scan-overrun pad

        if (am != 0) {
            const float2* dd2 = (const float2*)(ls_dir + pix * 18);
            const float* wv = ls_w + pix * 9;
            unsigned short r[28];
#pragma unroll
            for (int p = 0; p < NP; ++p) {
                float wx = wv[p];
                float e = __expf(wx);
                float sp = (wx > 15.f) ? wx : __logf(1.f + e);
                float2 nd = dd2[p];
                float nx = nd.x, ny = nd.y;
                float nn = nx * nx + ny * ny;
                float R00, R01, R11;
                if (nn > 0.f) {
                    float inv = __builtin_amdgcn_rcpf(nn);
                    R00 = sp * (1.f - nx * nx * inv);
                    R01 = -sp * (nx * ny * inv);
                    R11 = sp * (1.f - ny * ny * inv);
                } else {  // divide_no_nan: n == 0 -> R = w * I
                    R00 = sp; R01 = 0.f; R11 = sp;
                }
                r[p * 3 + 0] = f2bf(R00);
                r[p * 3 + 1] = f2bf(R01);
                r[p * 3 + 2] = f2bf(R11);
            }
            r[27] = 0;
            unsigned* row = ls_vals + pix * VROW;
#pragma unroll
            for (int k = 0; k < 14; ++k)
                row[k] = (unsigned)r[2 * k] | ((unsigned)r[2 * k + 1] << 16);
        }
    }
    __syncthreads();

    // ---- Phase B: 216 gather threads accumulate in registers ----
    float a0 = 0.f, a1 = 0.f, a2 = 0.f, a3 = 0.f, a4 = 0.f;
    if (tid < 216) {
        const int s  = tid % 3;
        const int pp = (tid / 3) % 9;
        const int cl = tid / 27;
        const int start = s * 86;
        const int end = (s == 2) ? TILE : start + 86;
        const unsigned short* v16 = (const unsigned short*)ls_vals;
        const float rowbase = (float)(blockIdx.x * 2) + 0.5f; // gh = blk*2 + (pix>>7)

        for (int i = start; i < end; i += 8) {
            int c8[8];
#pragma unroll
            for (int j = 0; j < 8; ++j) c8[j] = ls_cls[i + j];
#pragma unroll
            for (int j = 0; j < 8; ++j) {
                const int pix = i + j;
                if (pix < end && c8[j] == cl) {
                    const int bse = pix * (VROW * 2) + pp * 3;
                    float R00 = bf2f(v16[bse + 0]);
                    float R01 = bf2f(v16[bse + 1]);
                    float R11 = bf2f(v16[bse + 2]);
                    float ch = (rowbase + (float)(pix >> 7)) * 0.0078125f;
                    float cw = ((float)(pix & 127) + 0.5f) * 0.0078125f;
                    a0 += R00;
                    a1 += R01;
                    a2 += R11;
                    a3 += R00 * ch + R01 * cw;
                    a4 += R01 * ch + R11 * cw;
                }
            }
        }
        ls_merge[tid][0] = a0;
        ls_merge[tid][1] = a1;
        ls_merge[tid][2] = a2;
        ls_merge[tid][3] = a3;
        ls_merge[tid][4] = a4;
    }
    __syncthreads();

    // ---- merge 3 slices, write block partial ----
    if (tid < 72) {
        float* outp = partial + (long)(b * BPB + blockIdx.x) * ACC_PER + tid * 5;
#pragma unroll
        for (int f = 0; f < 5; ++f)
            outp[f] = ls_merge[tid * 3 + 0][f] + ls_merge[tid * 3 + 1][f] +
                      ls_merge[tid * 3 + 2][f];
    }
}

// Kernel 2: 4 lanes per (b,cls,p) sum 64 block partials in f64,
// butterfly-reduce, 2x2 solve, scale by HEIGHT=128.
__global__ void cls_vote_solve(const float* __restrict__ partial,
                               float* __restrict__ out)
{
    int t = blockIdx.x * blockDim.x + threadIdx.x;
    if (t >= Bsz * OC * NP * 4) return;
    const int g = t & 3;
    const int id = t >> 2;          // (b, cls*9+p)
    const int b = id / (OC * NP);
    const int r = id % (OC * NP);

    double a = 0, bb = 0, c = 0, q0 = 0, q1 = 0;
    const float* base = partial + (long)b * BPB * ACC_PER + r * 5;
#pragma unroll 4
    for (int blk = g; blk < BPB; blk += 4) {
        const float* pp = base + blk * ACC_PER;
        a  += (double)pp[0];
        bb += (double)pp[1];
        c  += (double)pp[2];
        q0 += (double)pp[3];
        q1 += (double)pp[4];
    }
#pragma unroll
    for (int off = 1; off < 4; off <<= 1) {
        a  += __shfl_xor(a, off, 64);
        bb += __shfl_xor(bb, off, 64);
        c  += __shfl_xor(c, off, 64);
        q0 += __shfl_xor(q0, off, 64);
        q1 += __shfl_xor(q1, off, 64);
    }
    if (g == 0) {
        double det = a * c - bb * bb;
        double p0 = 0.0, p1 = 0.0;
        if (det != 0.0) {
            double ia = c / det, ib = -bb / det, ic = a / det;
            p0 = ia * q0 + ib * q1;
            p1 = ib * q0 + ic * q1;
        }
        out[2 * id + 0] = (float)(p0 * 128.0);
        out[2 * id + 1] = (float)(p1 * 128.0);
    }
}

extern "C" void kernel_launch(void* const* d_in, const int* in_sizes, int n_in,
                              void* d_out, int out_size, void* d_ws, size_t ws_size,
                              hipStream_t stream) {
    const float* seg    = (const float*)d_in[0];
    const float* direct = (const float*)d_in[1];
    const float* wts    = (const float*)d_in[2];
    float* out = (float*)d_out;
    float* partial = (float*)d_ws;  // 512 * 360 * 4 = 737,280 B

    dim3 grid1(BPB, Bsz);
    cls_vote_partial<<<grid1, THREADS, 0, stream>>>(seg, direct, wts, partial);

    int total = Bsz * OC * NP * 4;  // 2304
    cls_vote_solve<<<(total + 255) / 256, 256, 0, stream>>>(partial, out);
}

// Round 7
// 15.491 us; speedup vs baseline: 6.4220x; 1.3799x over previous
//
#include <hip/hip_runtime.h>
#include <math.h>

#define Bsz 8
#define NP 9
#define OC 8
#define TILE 256           // pixels per block (2 image rows)
#define BPB 64             // blocks per batch
#define THREADS 256
#define ACC_PER (OC * NP * 5)    // 360 per-block partial values

// Kernel 1: per-block class-gather reduction, zero atomics.
// Phase A: argmax class per pixel + ballot-compacted per-class pixel lists.
// Phase B: 216 threads = (8 cls x 9 pts x 3 slices) walk their class list,
//          recompute softplus/R/q from staged dir/w, accumulate in registers.
__global__ __launch_bounds__(THREADS) void cls_vote_partial(
    const float* __restrict__ seg, const float* __restrict__ direct,
    const float* __restrict__ wts, float* __restrict__ partial)
{
    __shared__ float ls_seg[TILE * 9];          //  9216 B
    __shared__ float ls_dir[TILE * 18];         // 18432 B
    __shared__ float ls_w[TILE * 9];            //  9216 B
    __shared__ unsigned char ls_list[OC * TILE];//  2048 B (pixel idx per class)
    __shared__ int ls_cnt[4][OC];               //   128 B
    __shared__ int ls_off[4][OC];               //   128 B
    __shared__ int ls_total[OC];                //    32 B
    __shared__ float ls_merge[216][5];          //  4320 B   (~43.5 KB -> 3 blk/CU)

    const int b = blockIdx.y;
    const int tid = threadIdx.x;
    const int lane = tid & 63;
    const int w = tid >> 6;
    const long gbase = (long)b * 16384 + blockIdx.x * TILE;

    // ---- coalesced float4 staging (verified round 3) ----
    {
        const float4* gs = (const float4*)(seg + gbase * 9);     // 576 float4
        const float4* gd = (const float4*)(direct + gbase * 18); // 1152 float4
        const float4* gw = (const float4*)(wts + gbase * 9);     // 576 float4
        float4* s4 = (float4*)ls_seg;
        float4* d4 = (float4*)ls_dir;
        float4* w4 = (float4*)ls_w;
#pragma unroll
        for (int k = 0; k < 2; ++k) s4[tid + k * THREADS] = gs[tid + k * THREADS];
        if (tid < 64) s4[tid + 512] = gs[tid + 512];
#pragma unroll
        for (int k = 0; k < 4; ++k) d4[tid + k * THREADS] = gd[tid + k * THREADS];
        if (tid < 128) d4[tid + 1024] = gd[tid + 1024];
#pragma unroll
        for (int k = 0; k < 2; ++k) w4[tid + k * THREADS] = gw[tid + k * THREADS];
        if (tid < 64) w4[tid + 512] = gw[tid + 512];
    }
    __syncthreads();

    // ---- Phase A: argmax + ballot compaction into per-class lists ----
    int cls;
    int mypos = 0;
    {
        const float* s = ls_seg + tid * 9;
        float m = s[0];
        int am = 0;
#pragma unroll
        for (int c = 1; c < 9; ++c) {
            float v = s[c];
            if (v > m) { m = v; am = c; }
        }
        cls = am - 1;  // -1 = background

        const unsigned long long lt = (1ull << lane) - 1ull;
#pragma unroll
        for (int c = 0; c < OC; ++c) {
            unsigned long long mask = __ballot(cls == c);
            if (lane == 0) ls_cnt[w][c] = __popcll(mask);
            if (cls == c) mypos = __popcll(mask & lt);
        }
    }
    __syncthreads();

    if (tid < OC) {  // cross-wave exclusive prefix per class
        int base = 0;
#pragma unroll
        for (int ww = 0; ww < 4; ++ww) {
            ls_off[ww][tid] = base;
            base += ls_cnt[ww][tid];
        }
        ls_total[tid] = base;
    }
    __syncthreads();

    if (cls >= 0)
        ls_list[cls * TILE + ls_off[w][cls] + mypos] = (unsigned char)tid;
    __syncthreads();

    // ---- Phase B: gather over compacted lists, accumulate in registers ----
    if (tid < 216) {
        const int s  = tid % 3;
        const int pp = (tid / 3) % 9;
        const int cl = tid / 27;
        const int n = ls_total[cl];
        const unsigned char* list = ls_list + cl * TILE;
        const float rowbase = (float)(blockIdx.x * 2) + 0.5f;

        float a0 = 0.f, a1 = 0.f, a2 = 0.f, a3 = 0.f, a4 = 0.f;
        for (int k = s; k < n; k += 3) {
            const int pix = list[k];
            const float2 nd = *(const float2*)(ls_dir + pix * 18 + pp * 2);
            const float wx = ls_w[pix * 9 + pp];
            float e = __expf(wx);
            float sp = (wx > 15.f) ? wx : __logf(1.f + e);
            float nx = nd.x, ny = nd.y;
            float nn = nx * nx + ny * ny;
            float R00, R01, R11;
            if (nn > 0.f) {
                float inv = __builtin_amdgcn_rcpf(nn);
                R00 = sp * (1.f - nx * nx * inv);
                R01 = -sp * (nx * ny * inv);
                R11 = sp * (1.f - ny * ny * inv);
            } else {  // divide_no_nan: n == 0 -> R = w * I
                R00 = sp; R01 = 0.f; R11 = sp;
            }
            float ch = (rowbase + (float)(pix >> 7)) * 0.0078125f;
            float cw = ((float)(pix & 127) + 0.5f) * 0.0078125f;
            a0 += R00;
            a1 += R01;
            a2 += R11;
            a3 += R00 * ch + R01 * cw;
            a4 += R01 * ch + R11 * cw;
        }
        ls_merge[tid][0] = a0;
        ls_merge[tid][1] = a1;
        ls_merge[tid][2] = a2;
        ls_merge[tid][3] = a3;
        ls_merge[tid][4] = a4;
    }
    __syncthreads();

    // ---- merge 3 slices, write block partial ----
    if (tid < 72) {
        float* outp = partial + (long)(b * BPB + blockIdx.x) * ACC_PER + tid * 5;
#pragma unroll
        for (int f = 0; f < 5; ++f)
            outp[f] = ls_merge[tid * 3 + 0][f] + ls_merge[tid * 3 + 1][f] +
                      ls_merge[tid * 3 + 2][f];
    }
}

// Kernel 2: 4 lanes per (b,cls,p) sum 64 block partials in f64,
// butterfly-reduce, 2x2 solve, scale by HEIGHT=128.
__global__ void cls_vote_solve(const float* __restrict__ partial,
                               float* __restrict__ out)
{
    int t = blockIdx.x * blockDim.x + threadIdx.x;
    if (t >= Bsz * OC * NP * 4) return;
    const int g = t & 3;
    const int id = t >> 2;          // (b, cls*9+p)
    const int b = id / (OC * NP);
    const int r = id % (OC * NP);

    double a = 0, bb = 0, c = 0, q0 = 0, q1 = 0;
    const float* base = partial + (long)b * BPB * ACC_PER + r * 5;
#pragma unroll 4
    for (int blk = g; blk < BPB; blk += 4) {
        const float* pp = base + blk * ACC_PER;
        a  += (double)pp[0];
        bb += (double)pp[1];
        c  += (double)pp[2];
        q0 += (double)pp[3];
        q1 += (double)pp[4];
    }
#pragma unroll
    for (int off = 1; off < 4; off <<= 1) {
        a  += __shfl_xor(a, off, 64);
        bb += __shfl_xor(bb, off, 64);
        c  += __shfl_xor(c, off, 64);
        q0 += __shfl_xor(q0, off, 64);
        q1 += __shfl_xor(q1, off, 64);
    }
    if (g == 0) {
        double det = a * c - bb * bb;
        double p0 = 0.0, p1 = 0.0;
        if (det != 0.0) {
            double ia = c / det, ib = -bb / det, ic = a / det;
            p0 = ia * q0 + ib * q1;
            p1 = ib * q0 + ic * q1;
        }
        out[2 * id + 0] = (float)(p0 * 128.0);
        out[2 * id + 1] = (float)(p1 * 128.0);
    }
}

extern "C" void kernel_launch(void* const* d_in, const int* in_sizes, int n_in,
                              void* d_out, int out_size, void* d_ws, size_t ws_size,
                              hipStream_t stream) {
    const float* seg    = (const float*)d_in[0];
    const float* direct = (const float*)d_in[1];
    const float* wts    = (const float*)d_in[2];
    float* out = (float*)d_out;
    float* partial = (float*)d_ws;  // 512 * 360 * 4 = 737,280 B

    dim3 grid1(BPB, Bsz);
    cls_vote_partial<<<grid1, THREADS, 0, stream>>>(seg, direct, wts, partial);

    int total = Bsz * OC * NP * 4;  // 2304
    cls_vote_solve<<<(total + 255) / 256, 256, 0, stream>>>(partial, out);
}

// Round 8
// 14.115 us; speedup vs baseline: 7.0484x; 1.0975x over previous
//
#include <hip/hip_runtime.h>
#include <math.h>

#define Bsz 8
#define NP 9
#define OC 8
#define TILE 256           // pixels per block (2 image rows)
#define BPB 64             // blocks per batch
#define THREADS 256
#define NR 72              // (cls,pt) pairs

// Kernel 1: per-block class-gather reduction, zero atomics.
// Phase A: argmax class straight from global (9 scalar loads, L1-resident
//          lines) + ballot-compacted per-class pixel lists.
// Phase B: 216 threads = (8 cls x 9 pts x 3 slices) walk their class list,
//          recompute softplus/R/q from staged dir/w, accumulate in registers.
// Partial layout TRANSPOSED for k2 coalescing: [(b*72 + r)*64 + blk]*5 + f.
__global__ __launch_bounds__(THREADS) void cls_vote_partial(
    const float* __restrict__ seg, const float* __restrict__ direct,
    const float* __restrict__ wts, float* __restrict__ partial)
{
    __shared__ float ls_dir[TILE * 18];         // 18432 B
    __shared__ float ls_w[TILE * 9];            //  9216 B
    __shared__ unsigned char ls_list[OC * TILE];//  2048 B
    __shared__ int ls_cnt[4][OC];               //   128 B
    __shared__ int ls_off[4][OC];               //   128 B
    __shared__ int ls_total[OC];                //    32 B
    __shared__ float ls_merge[216][5];          //  4320 B  (~34.3 KB -> 4 blk/CU)

    const int b = blockIdx.y;
    const int tid = threadIdx.x;
    const int lane = tid & 63;
    const int w = tid >> 6;
    const long gbase = (long)b * 16384 + blockIdx.x * TILE;

    // ---- coalesced float4 staging of dir/w ----
    {
        const float4* gd = (const float4*)(direct + gbase * 18); // 1152 float4
        const float4* gw = (const float4*)(wts + gbase * 9);     // 576 float4
        float4* d4 = (float4*)ls_dir;
        float4* w4 = (float4*)ls_w;
#pragma unroll
        for (int k = 0; k < 4; ++k) d4[tid + k * THREADS] = gd[tid + k * THREADS];
        if (tid < 128) d4[tid + 1024] = gd[tid + 1024];
#pragma unroll
        for (int k = 0; k < 2; ++k) w4[tid + k * THREADS] = gw[tid + k * THREADS];
        if (tid < 64) w4[tid + 512] = gw[tid + 512];
    }

    // ---- Phase A: argmax from global + ballot compaction ----
    int cls;
    int mypos = 0;
    {
        const float* s = seg + (gbase + tid) * 9;
        float m = s[0];
        int am = 0;
#pragma unroll
        for (int c = 1; c < 9; ++c) {
            float v = s[c];
            if (v > m) { m = v; am = c; }
        }
        cls = am - 1;  // -1 = background

        const unsigned long long lt = (1ull << lane) - 1ull;
#pragma unroll
        for (int c = 0; c < OC; ++c) {
            unsigned long long mask = __ballot(cls == c);
            if (lane == 0) ls_cnt[w][c] = __popcll(mask);
            if (cls == c) mypos = __popcll(mask & lt);
        }
    }
    __syncthreads();

    if (tid < OC) {  // cross-wave exclusive prefix per class
        int base = 0;
#pragma unroll
        for (int ww = 0; ww < 4; ++ww) {
            ls_off[ww][tid] = base;
            base += ls_cnt[ww][tid];
        }
        ls_total[tid] = base;
    }
    __syncthreads();

    if (cls >= 0)
        ls_list[cls * TILE + ls_off[w][cls] + mypos] = (unsigned char)tid;
    __syncthreads();

    // ---- Phase B: gather over compacted lists, accumulate in registers ----
    if (tid < 216) {
        const int s  = tid % 3;
        const int pp = (tid / 3) % 9;
        const int cl = tid / 27;
        const int n = ls_total[cl];
        const unsigned char* list = ls_list + cl * TILE;
        const float rowbase = (float)(blockIdx.x * 2) + 0.5f;

        float a0 = 0.f, a1 = 0.f, a2 = 0.f, a3 = 0.f, a4 = 0.f;
        for (int k = s; k < n; k += 3) {
            const int pix = list[k];
            const float2 nd = *(const float2*)(ls_dir + pix * 18 + pp * 2);
            const float wx = ls_w[pix * 9 + pp];
            float e = __expf(wx);
            float sp = (wx > 15.f) ? wx : __logf(1.f + e);
            float nx = nd.x, ny = nd.y;
            float nn = nx * nx + ny * ny;
            float R00, R01, R11;
            if (nn > 0.f) {
                float inv = __builtin_amdgcn_rcpf(nn);
                R00 = sp * (1.f - nx * nx * inv);
                R01 = -sp * (nx * ny * inv);
                R11 = sp * (1.f - ny * ny * inv);
            } else {  // divide_no_nan: n == 0 -> R = w * I
                R00 = sp; R01 = 0.f; R11 = sp;
            }
            float ch = (rowbase + (float)(pix >> 7)) * 0.0078125f;
            float cw = ((float)(pix & 127) + 0.5f) * 0.0078125f;
            a0 += R00;
            a1 += R01;
            a2 += R11;
            a3 += R00 * ch + R01 * cw;
            a4 += R01 * ch + R11 * cw;
        }
        ls_merge[tid][0] = a0;
        ls_merge[tid][1] = a1;
        ls_merge[tid][2] = a2;
        ls_merge[tid][3] = a3;
        ls_merge[tid][4] = a4;
    }
    __syncthreads();

    // ---- merge 3 slices, write transposed block partial ----
    if (tid < NR) {
        float* outp = partial + ((long)(b * NR + tid) * BPB + blockIdx.x) * 5;
#pragma unroll
        for (int f = 0; f < 5; ++f)
            outp[f] = ls_merge[tid * 3 + 0][f] + ls_merge[tid * 3 + 1][f] +
                      ls_merge[tid * 3 + 2][f];
    }
}

// Kernel 2: one wave per (b,cls,pt). 64 lanes read 64 consecutive 20-B
// records (coalesced 1280 B), f64 butterfly reduce, lane 0 solves 2x2.
__global__ __launch_bounds__(256) void cls_vote_solve(
    const float* __restrict__ partial, float* __restrict__ out)
{
    const int wave = threadIdx.x >> 6;
    const int lane = threadIdx.x & 63;
    const int id = blockIdx.x * 4 + wave;   // (b*72 + r), r = cls*9+pt
    if (id >= Bsz * NR) return;

    const float* pp = partial + ((long)id * BPB + lane) * 5;
    double a  = (double)pp[0];
    double bb = (double)pp[1];
    double c  = (double)pp[2];
    double q0 = (double)pp[3];
    double q1 = (double)pp[4];

#pragma unroll
    for (int off = 1; off < 64; off <<= 1) {
        a  += __shfl_xor(a, off, 64);
        bb += __shfl_xor(bb, off, 64);
        c  += __shfl_xor(c, off, 64);
        q0 += __shfl_xor(q0, off, 64);
        q1 += __shfl_xor(q1, off, 64);
    }

    if (lane == 0) {
        double det = a * c - bb * bb;
        double p0 = 0.0, p1 = 0.0;
        if (det != 0.0) {
            double ia = c / det, ib = -bb / det, ic = a / det;
            p0 = ia * q0 + ib * q1;
            p1 = ib * q0 + ic * q1;
        }
        out[2 * id + 0] = (float)(p0 * 128.0);
        out[2 * id + 1] = (float)(p1 * 128.0);
    }
}

extern "C" void kernel_launch(void* const* d_in, const int* in_sizes, int n_in,
                              void* d_out, int out_size, void* d_ws, size_t ws_size,
                              hipStream_t stream) {
    const float* seg    = (const float*)d_in[0];
    const float* direct = (const float*)d_in[1];
    const float* wts    = (const float*)d_in[2];
    float* out = (float*)d_out;
    float* partial = (float*)d_ws;  // 8*72*64*5*4 = 737,280 B

    dim3 grid1(BPB, Bsz);
    cls_vote_partial<<<grid1, THREADS, 0, stream>>>(seg, direct, wts, partial);

    int nwaves = Bsz * NR;          // 576 waves, 4 per block
    cls_vote_solve<<<nwaves / 4, 256, 0, stream>>>(partial, out);
}